// Round 1
// baseline (439.790 us; speedup 1.0000x reference)
//
#include <hip/hip_runtime.h>
#include <hip/hip_bf16.h>

#define NROW 8192
#define DIM  128
#define BI   128
#define BJ   128
#define JSPLIT 4
#define STRIDE (DIM + 4)   // 132 floats: keeps 16B alignment, rotates banks by 4 per row

// ws layout (floats/uints):
//   [0, N)     float sqnorm
//   [N, 2N)    uint  pos bits (positive-float-as-uint, atomicMax)
//   [2N, 3N)   uint  neg bits (atomicMin)

__global__ __launch_bounds__(256) void prep_kernel(const float* __restrict__ x,
                                                   float* __restrict__ sq,
                                                   unsigned* __restrict__ posb,
                                                   unsigned* __restrict__ negb,
                                                   float* __restrict__ out) {
    int gtid = blockIdx.x * 256 + threadIdx.x;
    // init reductions
    if (gtid < NROW) {
        posb[gtid] = 0u;                        // 0.0f
        negb[gtid] = __float_as_uint(1.0e6f);   // BIG
    }
    if (gtid == 0) out[0] = 0.0f;
    // one wave (64 lanes) per row: row = gtid/64
    int row  = gtid >> 6;
    int lane = threadIdx.x & 63;
    if (row < NROW) {
        const float* xr = x + (size_t)row * DIM;
        float a = xr[lane];
        float b = xr[lane + 64];
        float s = a * a + b * b;
        #pragma unroll
        for (int o = 32; o > 0; o >>= 1) s += __shfl_down(s, o);
        if (lane == 0) sq[row] = s;
    }
}

__global__ __launch_bounds__(256, 1) void tri_main(const float* __restrict__ x,
                                                   const int* __restrict__ lbl,
                                                   const float* __restrict__ sq,
                                                   unsigned* __restrict__ posb,
                                                   unsigned* __restrict__ negb) {
    __shared__ float As[BI * STRIDE];   // 67584 B
    __shared__ float Bs[BJ * STRIDE];   // 67584 B  -> 132 KB total, 1 block/CU

    const int rb = blockIdx.x & 63;          // row-block
    const int jq = blockIdx.x >> 6;          // column quarter
    const int i0 = rb * BI;
    const int t  = threadIdx.x;
    const int tx = t & 15;
    const int ty = t >> 4;

    // ---- load A tile: 128 rows x 128 floats = 4096 float4, 16 per thread ----
    {
        const float4* src = (const float4*)(x + (size_t)i0 * DIM);
        #pragma unroll
        for (int f = t; f < BI * (DIM / 4); f += 256) {
            int row = f >> 5;        // /32 float4 per row
            int k4  = f & 31;
            float4 v = src[row * 32 + k4];
            *(float4*)&As[row * STRIDE + k4 * 4] = v;
        }
    }

    // per-thread i rows: i_local = ty + 16*ii
    float sq_i[8]; int lbl_i[8];
    #pragma unroll
    for (int ii = 0; ii < 8; ii++) {
        int ig = i0 + ty + 16 * ii;
        sq_i[ii]  = sq[ig];
        lbl_i[ii] = lbl[ig];
    }

    float pos[8], neg[8];
    #pragma unroll
    for (int ii = 0; ii < 8; ii++) { pos[ii] = 0.0f; neg[ii] = 1.0e6f; }

    const int NTILE = (NROW / JSPLIT) / BJ;   // 16
    for (int jt = 0; jt < NTILE; jt++) {
        const int j0 = jq * (NROW / JSPLIT) + jt * BJ;
        __syncthreads();   // protect Bs (previous iteration's reads done)
        {
            const float4* src = (const float4*)(x + (size_t)j0 * DIM);
            #pragma unroll
            for (int f = t; f < BJ * (DIM / 4); f += 256) {
                int row = f >> 5;
                int k4  = f & 31;
                float4 v = src[row * 32 + k4];
                *(float4*)&Bs[row * STRIDE + k4 * 4] = v;
            }
        }
        __syncthreads();

        float acc[8][8];
        #pragma unroll
        for (int ii = 0; ii < 8; ii++)
            #pragma unroll
            for (int jj = 0; jj < 8; jj++) acc[ii][jj] = 0.0f;

        for (int k4 = 0; k4 < DIM / 4; k4++) {
            float4 a[8], b[8];
            #pragma unroll
            for (int ii = 0; ii < 8; ii++)
                a[ii] = *(const float4*)&As[(ty + 16 * ii) * STRIDE + k4 * 4];
            #pragma unroll
            for (int jj = 0; jj < 8; jj++)
                b[jj] = *(const float4*)&Bs[(tx + 16 * jj) * STRIDE + k4 * 4];
            #pragma unroll
            for (int ii = 0; ii < 8; ii++)
                #pragma unroll
                for (int jj = 0; jj < 8; jj++) {
                    acc[ii][jj] += a[ii].x * b[jj].x;
                    acc[ii][jj] += a[ii].y * b[jj].y;
                    acc[ii][jj] += a[ii].z * b[jj].z;
                    acc[ii][jj] += a[ii].w * b[jj].w;
                }
        }

        // epilogue: distances + mask updates
        #pragma unroll
        for (int jj = 0; jj < 8; jj++) {
            int jg = j0 + tx + 16 * jj;
            float sqj = sq[jg];
            int lj = lbl[jg];
            #pragma unroll
            for (int ii = 0; ii < 8; ii++) {
                float d2 = sq_i[ii] + sqj - 2.0f * acc[ii][jj];
                d2 = fmaxf(d2, 0.0f);
                float dist = (d2 > 0.0f) ? sqrtf(d2) : 0.0f;
                int ig = i0 + ty + 16 * ii;
                bool same = (lbl_i[ii] == lj);
                if (same) {
                    if (ig != jg) pos[ii] = fmaxf(pos[ii], dist);
                } else {
                    neg[ii] = fminf(neg[ii], dist);
                }
            }
        }
    }

    // ---- reduce pos/neg across the 16 tx threads sharing each i ----
    __syncthreads();
    float* red = As;   // reuse: need 128*16 = 2048 floats
    #pragma unroll
    for (int ii = 0; ii < 8; ii++) red[(ty + 16 * ii) * 16 + tx] = pos[ii];
    __syncthreads();
    if (t < BI) {
        float m = red[t * 16];
        #pragma unroll
        for (int q = 1; q < 16; q++) m = fmaxf(m, red[t * 16 + q]);
        atomicMax(&posb[i0 + t], __float_as_uint(m));
    }
    __syncthreads();
    #pragma unroll
    for (int ii = 0; ii < 8; ii++) red[(ty + 16 * ii) * 16 + tx] = neg[ii];
    __syncthreads();
    if (t < BI) {
        float m = red[t * 16];
        #pragma unroll
        for (int q = 1; q < 16; q++) m = fminf(m, red[t * 16 + q]);
        atomicMin(&negb[i0 + t], __float_as_uint(m));
    }
}

__global__ __launch_bounds__(256) void tri_final(const unsigned* __restrict__ posb,
                                                 const unsigned* __restrict__ negb,
                                                 const float* __restrict__ margin,
                                                 float* __restrict__ out) {
    int r = blockIdx.x * 256 + threadIdx.x;
    float m = margin[0];
    float loss = 0.0f;
    if (r < NROW) {
        float p  = __uint_as_float(posb[r]);
        float ng = __uint_as_float(negb[r]);
        loss = fmaxf(p - ng + m, 0.0f) * (1.0f / (float)NROW);
    }
    #pragma unroll
    for (int o = 32; o > 0; o >>= 1) loss += __shfl_down(loss, o);
    __shared__ float wsum[4];
    int lane = threadIdx.x & 63, w = threadIdx.x >> 6;
    if (lane == 0) wsum[w] = loss;
    __syncthreads();
    if (threadIdx.x == 0) {
        atomicAdd(out, wsum[0] + wsum[1] + wsum[2] + wsum[3]);
    }
}

extern "C" void kernel_launch(void* const* d_in, const int* in_sizes, int n_in,
                              void* d_out, int out_size, void* d_ws, size_t ws_size,
                              hipStream_t stream) {
    const float* x      = (const float*)d_in[0];
    const int*   lbl    = (const int*)d_in[1];
    const float* margin = (const float*)d_in[2];
    float* out = (float*)d_out;

    float*    sq   = (float*)d_ws;
    unsigned* posb = (unsigned*)d_ws + NROW;
    unsigned* negb = (unsigned*)d_ws + 2 * NROW;

    // one wave per row -> 8192 waves -> 2048 blocks of 256
    prep_kernel<<<2048, 256, 0, stream>>>(x, sq, posb, negb, out);
    tri_main<<<64 * JSPLIT, 256, 0, stream>>>(x, lbl, sq, posb, negb);
    tri_final<<<NROW / 256, 256, 0, stream>>>(posb, negb, margin, out);
}

// Round 2
// 90.681 us; speedup vs baseline: 4.8499x; 4.8499x over previous
//
#include <hip/hip_runtime.h>
#include <hip/hip_bf16.h>

#define NROW 8192
#define DIM  128
#define BI   128
#define BJ   128
#define JSPLIT 8
#define LSTR 136            // bf16 elems per LDS row: 128 + 8 pad (272 B -> 2-way banks = free)
#define BIGF 1e30f

typedef __attribute__((ext_vector_type(8))) short bf16x8;
typedef __attribute__((ext_vector_type(4))) float f32x4;

// ws layout (bytes):
//   [0, 2 MB)            xb   : 8192x128 bf16 (ushort)
//   [+0, +32 KB)         sq   : 8192 f32 row sq-norms (fp32-exact)
//   [+32, +64 KB)        posb : 8192 u32 (d^2 as float bits, atomicMax)
//   [+64, +96 KB)        negb : 8192 u32 (d^2 as float bits, atomicMin)

__device__ __forceinline__ unsigned short f2bf(float f) {
    unsigned u = __float_as_uint(f);
    unsigned r = (u + 0x7fffu + ((u >> 16) & 1u)) >> 16;   // RNE
    return (unsigned short)r;
}

__global__ __launch_bounds__(256) void prep_kernel(const float* __restrict__ x,
                                                   unsigned short* __restrict__ xb,
                                                   float* __restrict__ sq,
                                                   unsigned* __restrict__ posb,
                                                   unsigned* __restrict__ negb,
                                                   float* __restrict__ out) {
    int gtid = blockIdx.x * 256 + threadIdx.x;
    if (gtid < NROW) {
        posb[gtid] = 0u;                       // 0.0f
        negb[gtid] = __float_as_uint(BIGF);
    }
    if (gtid == 0) out[0] = 0.0f;
    // one wave per row (grid 2048*256/64 == 8192 rows exactly)
    int row  = gtid >> 6;
    int lane = threadIdx.x & 63;
    const float* xr = x + (size_t)row * DIM;
    float a = xr[lane];
    float b = xr[lane + 64];
    xb[(size_t)row * DIM + lane]      = f2bf(a);
    xb[(size_t)row * DIM + lane + 64] = f2bf(b);
    float s = a * a + b * b;
    #pragma unroll
    for (int o = 32; o > 0; o >>= 1) s += __shfl_down(s, o);
    if (lane == 0) sq[row] = s;
}

__global__ __launch_bounds__(256, 2) void tri_mfma(const unsigned short* __restrict__ xb,
                                                   const int* __restrict__ lbl,
                                                   const float* __restrict__ sq,
                                                   unsigned* __restrict__ posb,
                                                   unsigned* __restrict__ negb) {
    __shared__ unsigned short As[BI * LSTR];   // 34816 B
    __shared__ unsigned short Bs[BJ * LSTR];   // 34816 B -> 69632 total, 2 blocks/CU

    const int bid = blockIdx.x;
    const int rb  = bid >> 3;        // 0..63 row-block
    const int jq  = bid & 7;         // 0..7 column split
    const int i0  = rb * BI;
    const int t    = threadIdx.x;
    const int lane = t & 63;
    const int w    = t >> 6;
    const int wrow = (w >> 1) * 64;  // wave 2x2 grid over the 128x128 tile
    const int wcol = (w & 1) * 64;
    const int quad = lane >> 4;
    const int l15  = lane & 15;

    // ---- stage A tile once: 128 rows x 256 B, padded rows ----
    {
        const int srow = t >> 4;     // 0..15
        const int schk = t & 15;     // 16B chunk
        #pragma unroll
        for (int it = 0; it < 8; it++) {
            int row = srow + it * 16;
            uint4 v = *(const uint4*)(xb + (size_t)(i0 + row) * DIM + schk * 8);
            *(uint4*)(&As[row * LSTR + schk * 8]) = v;
        }
    }

    // per-lane row metadata: rows i0 + wrow + ti*16 + quad*4 + r
    float sqi[4][4];
    int   lbli[4][4];
    #pragma unroll
    for (int ti = 0; ti < 4; ti++) {
        int rbase = i0 + wrow + ti * 16 + quad * 4;
        float4 s4 = *(const float4*)(sq + rbase);
        int4   l4 = *(const int4*)(lbl + rbase);
        sqi[ti][0] = s4.x; sqi[ti][1] = s4.y; sqi[ti][2] = s4.z; sqi[ti][3] = s4.w;
        lbli[ti][0] = l4.x; lbli[ti][1] = l4.y; lbli[ti][2] = l4.z; lbli[ti][3] = l4.w;
    }

    // running s = (sq_j - 2*dot) extrema; d^2 = sq_i + s added at the end
    float posm[4][4], negm[4][4];
    #pragma unroll
    for (int ti = 0; ti < 4; ti++)
        #pragma unroll
        for (int r = 0; r < 4; r++) { posm[ti][r] = -BIGF; negm[ti][r] = BIGF; }

    #pragma unroll 1
    for (int jt = 0; jt < (NROW / JSPLIT) / BJ; jt++) {
        const int j0 = jq * (NROW / JSPLIT) + jt * BJ;
        __syncthreads();             // previous Bs reads done
        {
            const int srow = t >> 4;
            const int schk = t & 15;
            #pragma unroll
            for (int it = 0; it < 8; it++) {
                int row = srow + it * 16;
                uint4 v = *(const uint4*)(xb + (size_t)(j0 + row) * DIM + schk * 8);
                *(uint4*)(&Bs[row * LSTR + schk * 8]) = v;
            }
        }
        __syncthreads();

        // column metadata (broadcast loads, L2-resident)
        float sqj[4]; int lblj[4];
        #pragma unroll
        for (int tj = 0; tj < 4; tj++) {
            int c = j0 + wcol + tj * 16 + l15;
            sqj[tj]  = sq[c];
            lblj[tj] = lbl[c];
        }

        f32x4 acc[4][4];
        #pragma unroll
        for (int ti = 0; ti < 4; ti++)
            #pragma unroll
            for (int tj = 0; tj < 4; tj++) acc[ti][tj] = (f32x4){0.f, 0.f, 0.f, 0.f};

        #pragma unroll
        for (int ks = 0; ks < 4; ks++) {
            bf16x8 af[4], bfr[4];
            #pragma unroll
            for (int ti = 0; ti < 4; ti++)
                af[ti] = *(const bf16x8*)(&As[(wrow + ti * 16 + l15) * LSTR + ks * 32 + quad * 8]);
            #pragma unroll
            for (int tj = 0; tj < 4; tj++)
                bfr[tj] = *(const bf16x8*)(&Bs[(wcol + tj * 16 + l15) * LSTR + ks * 32 + quad * 8]);
            #pragma unroll
            for (int ti = 0; ti < 4; ti++)
                #pragma unroll
                for (int tj = 0; tj < 4; tj++)
                    acc[ti][tj] = __builtin_amdgcn_mfma_f32_16x16x32_bf16(af[ti], bfr[tj], acc[ti][tj], 0, 0, 0);
        }

        const bool diag = (i0 + wrow) == (j0 + wcol);   // wave tile touches the diagonal
        #pragma unroll
        for (int ti = 0; ti < 4; ti++)
            #pragma unroll
            for (int tj = 0; tj < 4; tj++)
                #pragma unroll
                for (int r = 0; r < 4; r++) {
                    float s = fmaf(-2.0f, acc[ti][tj][r], sqj[tj]);
                    bool same = (lbli[ti][r] == lblj[tj]);
                    bool isd  = diag && (ti == tj) && (quad * 4 + r == l15);
                    float sp = (same && !isd) ? s : -BIGF;
                    float sn = same ? BIGF : s;
                    posm[ti][r] = fmaxf(posm[ti][r], sp);
                    negm[ti][r] = fminf(negm[ti][r], sn);
                }
    }

    // reduce across the 16 column-lanes sharing each row; then one atomic per row
    #pragma unroll
    for (int ti = 0; ti < 4; ti++)
        #pragma unroll
        for (int r = 0; r < 4; r++) {
            float p = posm[ti][r];
            float n = negm[ti][r];
            #pragma unroll
            for (int m = 8; m >= 1; m >>= 1) {
                p = fmaxf(p, __shfl_xor(p, m));
                n = fminf(n, __shfl_xor(n, m));
            }
            if (l15 == 0) {
                int row = i0 + wrow + ti * 16 + quad * 4 + r;
                float d2p = fmaxf(0.0f, sqi[ti][r] + p);   // no positive -> 0
                float d2n = fmaxf(0.0f, sqi[ti][r] + n);   // clamp bf16-noise negatives
                atomicMax(&posb[row], __float_as_uint(d2p));
                atomicMin(&negb[row], __float_as_uint(d2n));
            }
        }
}

__global__ __launch_bounds__(256) void tri_final(const unsigned* __restrict__ posb,
                                                 const unsigned* __restrict__ negb,
                                                 const float* __restrict__ margin,
                                                 float* __restrict__ out) {
    int r = blockIdx.x * 256 + threadIdx.x;
    float m = margin[0];
    float p  = sqrtf(__uint_as_float(posb[r]));
    float ng = sqrtf(__uint_as_float(negb[r]));
    float loss = fmaxf(p - ng + m, 0.0f) * (1.0f / (float)NROW);
    #pragma unroll
    for (int o = 32; o > 0; o >>= 1) loss += __shfl_down(loss, o);
    __shared__ float wsum[4];
    int lane = threadIdx.x & 63, wv = threadIdx.x >> 6;
    if (lane == 0) wsum[wv] = loss;
    __syncthreads();
    if (threadIdx.x == 0) atomicAdd(out, wsum[0] + wsum[1] + wsum[2] + wsum[3]);
}

extern "C" void kernel_launch(void* const* d_in, const int* in_sizes, int n_in,
                              void* d_out, int out_size, void* d_ws, size_t ws_size,
                              hipStream_t stream) {
    const float* x      = (const float*)d_in[0];
    const int*   lbl    = (const int*)d_in[1];
    const float* margin = (const float*)d_in[2];
    float* out = (float*)d_out;

    unsigned short* xb = (unsigned short*)d_ws;                       // 2 MB
    float*    sq   = (float*)((char*)d_ws + (size_t)NROW * DIM * 2);
    unsigned* posb = (unsigned*)((char*)sq + NROW * 4);
    unsigned* negb = posb + NROW;

    prep_kernel<<<2048, 256, 0, stream>>>(x, xb, sq, posb, negb, out);
    tri_mfma<<<64 * JSPLIT, 256, 0, stream>>>(xb, lbl, sq, posb, negb);
    tri_final<<<NROW / 256, 256, 0, stream>>>(posb, negb, margin, out);
}